// Round 4
// baseline (202.421 us; speedup 1.0000x reference)
//
#include <hip/hip_runtime.h>
#include <hip/hip_fp16.h>
#include <cmath>

// SVC_63737314673237 round 7: stall attack on the R6 structure.
// R6 post-mortem: MFMA/DS/VALU each ~27% busy, >45% all-idle => stall-bound.
// (1) sv-half split: grid (64,10,2) = 1280 blocks = uniform 5/CU at
//     2-resident -> kills the 640@2.5/CU tail (-17% makespan). Each T slot
//     gets exactly 2 atomicAdds (2-addend f32 sum is order-exact).
// (2) cross-phase drain: {vmcnt(0); s_barrier; issue stage(p+1)} at phase
//     TOP -> stage(p) gets a full phase of cover before its drain, and
//     vmcnt-then-barrier makes the landing guarantee collective.
// (3) s_setprio(1) around the MFMA cluster (T5; blocks are de-phased).
// Math identical to verified R5/R6: split-f16 3-pass GEMM, kv C-tile ==
// 16x16x16 B-frag PV-MFMA reduce, zero-padded ahp + clamped sv rows.

#define GAMMA 0.01f
constexpr int N  = 8192;
constexpr int D  = 256;
constexpr int S  = 5000;
constexpr int C  = 10;
constexpr int NV = 500;
constexpr int R  = 9;     // C-1
constexpr int SPAD = 5120; // 10 classes x 512 padded cols

typedef _Float16 f16x8 __attribute__((ext_vector_type(8)));
typedef _Float16 f16x4 __attribute__((ext_vector_type(4)));
typedef float    f32x4 __attribute__((ext_vector_type(4)));

__device__ __forceinline__ void gload16(const void* g, void* l) {
    __builtin_amdgcn_global_load_lds(
        (const __attribute__((address_space(1))) void*)g,
        (__attribute__((address_space(3))) void*)l, 16, 0, 0);
}

// ---------------- fused split + norms: one wave per row ---------------------
__global__ __launch_bounds__(256) void prep_kernel(const float* __restrict__ x,
                                                   const float* __restrict__ sv,
                                                   _Float16* __restrict__ xh,
                                                   _Float16* __restrict__ xl,
                                                   _Float16* __restrict__ sh,
                                                   _Float16* __restrict__ sl,
                                                   float* __restrict__ xn,
                                                   float* __restrict__ svn) {
    int gid  = blockIdx.x * blockDim.x + threadIdx.x;
    int wid  = gid >> 6;
    int lane = gid & 63;
    if (wid >= N + S) return;
    bool isx = wid < N;
    int  r   = isx ? wid : wid - N;
    const float* row = isx ? (x + (size_t)r * D) : (sv + (size_t)r * D);
    float4 v = reinterpret_cast<const float4*>(row)[lane];
    float s = v.x * v.x + v.y * v.y + v.z * v.z + v.w * v.w;
#pragma unroll
    for (int off = 32; off > 0; off >>= 1) s += __shfl_xor(s, off, 64);
    float vv[4] = {v.x, v.y, v.z, v.w};
    f16x4 h, l;
#pragma unroll
    for (int k = 0; k < 4; ++k) {
        _Float16 hi = (_Float16)vv[k];
        h[k] = hi;
        l[k] = (_Float16)((vv[k] - (float)hi) * 4096.0f);
    }
    size_t o = (size_t)r * D + lane * 4;
    *(f16x4*)((isx ? xh : sh) + o) = h;
    *(f16x4*)((isx ? xl : sl) + o) = l;
    if (lane == 0) (isx ? xn : svn)[r] = s;
}

// ---------------- a split + padded svnorm + T zero --------------------------
__global__ __launch_bounds__(256) void prep_a(const float* __restrict__ a,
                                              const float* __restrict__ svn,
                                              _Float16* __restrict__ ah,
                                              _Float16* __restrict__ al,
                                              float* __restrict__ svnp,
                                              float* __restrict__ T) {
    int idx = blockIdx.x * 256 + threadIdx.x;
    // zero T: N*90 floats over 16*SPAD threads (9 each)
    for (int t = idx; t < N * 90; t += 16 * SPAD) T[t] = 0.0f;
    if (idx >= 16 * SPAD) return;
    int r = idx / SPAD, col = idx - r * SPAD;
    int cls = col >> 9, j = col & 511;
    int s = cls * NV + ((j < NV) ? j : NV - 1);
    float av = (r < R && j < NV) ? a[(size_t)r * S + s] : 0.0f;
    _Float16 h = (_Float16)av;
    ah[idx] = h;
    al[idx] = (_Float16)((av - (float)h) * 4096.0f);
    if (r == 0) svnp[col] = svn[s];
}

// ---------------- swapped split-MFMA GEMM + exp + PV-MFMA reduce ------------
// grid: (64 n-tiles of 128, 10 classes, 2 sv-halves) = 1280 blocks, uniform
// 5 blocks/CU at 2-resident. block 256 = 4 waves (wm,wn 2x2), wave tile
// 64sv x 64n = 4x4 mfma tiles. 16 phases = 2 sv-chunks x 8 kb.
// Per phase: vmcnt(0)+s_barrier (drain covered by prev phase), issue next
// stage, frag reads, setprio-wrapped MFMAs, chunk epilogue at kb==7.
__global__ __launch_bounds__(256, 2) void svc_gemm(const _Float16* __restrict__ xh,
                                                   const _Float16* __restrict__ xl,
                                                   const _Float16* __restrict__ sh,
                                                   const _Float16* __restrict__ sl,
                                                   const _Float16* __restrict__ ahp,
                                                   const _Float16* __restrict__ alp,
                                                   const float* __restrict__ xnorm,
                                                   const float* __restrict__ svnp,
                                                   float* __restrict__ T) {
    __shared__ _Float16 SVs[2][2][128 * 32];  // 32KB: M-operand (sv rows)
    __shared__ _Float16 Xs[2][2][128 * 32];   // 32KB: N-operand (x rows)

    const int tid  = threadIdx.x;
    const int n0   = blockIdx.x * 128;
    const int cls  = blockIdx.y;
    const int ch0  = blockIdx.z * 2;   // this block's 2 sv-chunks
    const int w    = tid >> 6;
    const int lane = tid & 63;
    const int wm   = w >> 1;   // splits 128 m
    const int wn   = w & 1;    // splits 128 n
    const int lx   = lane & 15;
    const int quad = lane >> 4;

    float xnr[4];
#pragma unroll
    for (int nt = 0; nt < 4; ++nt)
        xnr[nt] = xnorm[n0 + wn * 64 + nt * 16 + lx];

    // fragment read offsets (f16 units), inverse of staged K-slot perm
    int svoff[4], xoff[4];
#pragma unroll
    for (int mt = 0; mt < 4; ++mt) {
        int row = wm * 64 + mt * 16 + lx;
        svoff[mt] = row * 32 + ((quad - row) & 3) * 8;
    }
#pragma unroll
    for (int nt = 0; nt < 4; ++nt) {
        int row = wn * 64 + nt * 16 + lx;
        xoff[nt] = row * 32 + ((quad - row) & 3) * 8;
    }

    // staging: linear LDS dest (wave-uniform base + lane*16B), swizzle on
    // the global K-offset
    const int arow = tid >> 2, ag = tid & 3;
    const int sg   = (ag + arow) & 3;
    const int segend = cls * NV + NV - 1;
    const int ldsw = w * 512;

    auto stage = [&](int ph, int buf) {
        const int ch = ch0 + (ph >> 3), kb = ph & 7;
        const size_t koff = (size_t)(kb * 32 + sg * 8);
        const size_t goX0 = (size_t)(n0 + arow) * D + koff;
        const size_t goX1 = (size_t)(n0 + arow + 64) * D + koff;
        gload16(xh + goX0, &Xs[buf][0][ldsw]);
        gload16(xl + goX0, &Xs[buf][1][ldsw]);
        gload16(xh + goX1, &Xs[buf][0][2048 + ldsw]);
        gload16(xl + goX1, &Xs[buf][1][2048 + ldsw]);
        const int svbase = cls * NV + ch * 128;
        int svr0 = svbase + arow;      if (svr0 > segend) svr0 = segend;
        int svr1 = svbase + arow + 64; if (svr1 > segend) svr1 = segend;
        const size_t go0 = (size_t)svr0 * D + koff;
        const size_t go1 = (size_t)svr1 * D + koff;
        gload16(sh + go0, &SVs[buf][0][ldsw]);
        gload16(sl + go0, &SVs[buf][1][ldsw]);
        gload16(sh + go1, &SVs[buf][0][2048 + ldsw]);
        gload16(sl + go1, &SVs[buf][1][2048 + ldsw]);
    };

    f32x4 accM[4][4], accC[4][4];      // first-GEMM tiles [mt][nt]
#pragma unroll
    for (int mt = 0; mt < 4; ++mt)
#pragma unroll
        for (int nt = 0; nt < 4; ++nt) {
            accM[mt][nt] = (f32x4){0.f, 0.f, 0.f, 0.f};
            accC[mt][nt] = (f32x4){0.f, 0.f, 0.f, 0.f};
        }
    f32x4 accO[4], accOC[4];           // PV output tiles [nt] (r x n)
#pragma unroll
    for (int nt = 0; nt < 4; ++nt) {
        accO[nt]  = (f32x4){0.f, 0.f, 0.f, 0.f};
        accOC[nt] = (f32x4){0.f, 0.f, 0.f, 0.f};
    }

    stage(0, 0);

    for (int ph = 0; ph < 16; ++ph) {
        const int buf = ph & 1;
        // drain stage(ph) (issued a full phase ago), then collective barrier:
        // after this, ALL waves' stage(ph) landed and all waves are done
        // reading buf^1 (phase ph-1) -> safe to overwrite it.
        asm volatile("s_waitcnt vmcnt(0)" ::: "memory");
        __builtin_amdgcn_s_barrier();
        asm volatile("" ::: "memory");
        if (ph < 15) stage(ph + 1, buf ^ 1);   // lands during THIS phase +next

        f16x8 Bx0[4], Bx1[4];
#pragma unroll
        for (int nt = 0; nt < 4; ++nt) {
            Bx0[nt] = *(const f16x8*)(&Xs[buf][0][xoff[nt]]);
            Bx1[nt] = *(const f16x8*)(&Xs[buf][1][xoff[nt]]);
        }
        __builtin_amdgcn_s_setprio(1);
#pragma unroll
        for (int mt = 0; mt < 4; ++mt) {
            f16x8 a0 = *(const f16x8*)(&SVs[buf][0][svoff[mt]]);
            f16x8 a1 = *(const f16x8*)(&SVs[buf][1][svoff[mt]]);
#pragma unroll
            for (int nt = 0; nt < 4; ++nt) {
                accM[mt][nt] = __builtin_amdgcn_mfma_f32_16x16x32_f16(
                    a0, Bx0[nt], accM[mt][nt], 0, 0, 0);
                accC[mt][nt] = __builtin_amdgcn_mfma_f32_16x16x32_f16(
                    a0, Bx1[nt], accC[mt][nt], 0, 0, 0);
                accC[mt][nt] = __builtin_amdgcn_mfma_f32_16x16x32_f16(
                    a1, Bx0[nt], accC[mt][nt], 0, 0, 0);
            }
        }
        __builtin_amdgcn_s_setprio(0);

        if ((ph & 7) == 7) {   // chunk done: exp + PV-MFMA reduce (no LDS)
            const int ch = ch0 + (ph >> 3);
            const int mbase = cls * 512 + ch * 128 + wm * 64;
#pragma unroll
            for (int mt = 0; mt < 4; ++mt) {
                const size_t ao = (size_t)lx * SPAD + mbase + mt * 16 + quad * 4;
                f16x4 afh = *(const f16x4*)(ahp + ao);   // A-frag: a[r=lx, k]
                f16x4 afl = *(const f16x4*)(alp + ao);
                float4 sn4 = *(const float4*)(svnp + mbase + mt * 16 + quad * 4);
#pragma unroll
                for (int nt = 0; nt < 4; ++nt) {
                    f16x4 bh, bl;   // B-frag: kv[k = quad*4+reg, col = lx]
#pragma unroll
                    for (int reg = 0; reg < 4; ++reg) {
                        float dot = accM[mt][nt][reg]
                                  + accC[mt][nt][reg] * (1.0f / 4096.0f);
                        float e  = fmaf(2.0f * GAMMA, dot,
                                        -GAMMA * (xnr[nt] + sn4[reg]));
                        float kv = __expf(e);
                        _Float16 h = (_Float16)kv;
                        bh[reg] = h;
                        bl[reg] = (_Float16)((kv - (float)h) * 4096.0f);
                    }
                    accO[nt]  = __builtin_amdgcn_mfma_f32_16x16x16f16(
                        afh, bh, accO[nt], 0, 0, 0);
                    accOC[nt] = __builtin_amdgcn_mfma_f32_16x16x16f16(
                        afh, bl, accOC[nt], 0, 0, 0);
                    accOC[nt] = __builtin_amdgcn_mfma_f32_16x16x16f16(
                        afl, bh, accOC[nt], 0, 0, 0);
                    accM[mt][nt] = (f32x4){0.f, 0.f, 0.f, 0.f};
                    accC[mt][nt] = (f32x4){0.f, 0.f, 0.f, 0.f};
                }
            }
        }
    }

    // cross-wm reduce via reused SVs buf0 (last read at ph 14; ph 15 reads
    // buf1, so no overlap), then 2-addend-exact atomicAdd into T.
    float* scr = (float*)&SVs[0][0][0];
    if (wm == 0) {
#pragma unroll
        for (int nt = 0; nt < 4; ++nt)
#pragma unroll
            for (int reg = 0; reg < 4; ++reg) {
                int base = ((wn * 4 + nt) * 2) * 256 + (quad * 4 + reg) * 16 + lx;
                scr[base]       = accO[nt][reg];
                scr[base + 256] = accOC[nt][reg];
            }
    }
    __syncthreads();
    if (wm == 1) {
#pragma unroll
        for (int nt = 0; nt < 4; ++nt)
#pragma unroll
            for (int reg = 0; reg < 4; ++reg) {
                int r = quad * 4 + reg;
                if (r < R) {
                    int base = ((wn * 4 + nt) * 2) * 256 + r * 16 + lx;
                    float o  = accO[nt][reg]  + scr[base];
                    float oc = accOC[nt][reg] + scr[base + 256];
                    int n = n0 + wn * 64 + nt * 16 + lx;
                    atomicAdd(&T[(size_t)n * 90 + r * 10 + cls],
                              o + oc * (1.0f / 4096.0f));
                }
            }
    }
}

// ---------------- pairwise voting + argmax ----------------------------------
__global__ __launch_bounds__(256) void vote_kernel(const float* __restrict__ T,
                                                   const float* __restrict__ b,
                                                   int* __restrict__ out) {
    int n = blockIdx.x * blockDim.x + threadIdx.x;
    if (n >= N) return;
    const float* Tn = T + (size_t)n * 90;
    float tv[90];
#pragma unroll
    for (int i = 0; i < 90; ++i) tv[i] = Tn[i];
    int counts[C];
#pragma unroll
    for (int k = 0; k < C; ++k) counts[k] = 0;
    int p = 0;
#pragma unroll
    for (int i = 0; i < C; ++i) {
#pragma unroll
        for (int j = i + 1; j < C; ++j) {
            float c = tv[i * 10 + j] + tv[(j - 1) * 10 + i] + b[p];
            if (c > 0.f) counts[i]++; else counts[j]++;
            ++p;
        }
    }
    int best = 0;
#pragma unroll
    for (int k = 1; k < C; ++k)
        if (counts[k] > counts[best]) best = k;
    out[n]     = best;
    out[N + n] = best;
}

extern "C" void kernel_launch(void* const* d_in, const int* in_sizes, int n_in,
                              void* d_out, int out_size, void* d_ws, size_t ws_size,
                              hipStream_t stream) {
    const float* x  = (const float*)d_in[0];   // [8192,256]
    const float* sv = (const float*)d_in[1];   // [5000,256]
    const float* a  = (const float*)d_in[2];   // [9,5000]
    const float* b  = (const float*)d_in[3];   // [45]
    int* out = (int*)d_out;

    char* wp = (char*)d_ws;
    _Float16* xh = (_Float16*)wp;  wp += (size_t)N * D * 2;
    _Float16* xl = (_Float16*)wp;  wp += (size_t)N * D * 2;
    _Float16* sh = (_Float16*)wp;  wp += (size_t)S * D * 2;
    _Float16* sl = (_Float16*)wp;  wp += (size_t)S * D * 2;
    float* xnorm  = (float*)wp;    wp += (size_t)N * 4;
    float* svnorm = (float*)wp;    wp += (size_t)S * 4;
    _Float16* ahp = (_Float16*)wp; wp += (size_t)16 * SPAD * 2;
    _Float16* alp = (_Float16*)wp; wp += (size_t)16 * SPAD * 2;
    float* svnp   = (float*)wp;    wp += (size_t)SPAD * 4;
    float* T      = (float*)wp;

    {   // fused split + norms: one wave per row
        int waves = N + S;
        prep_kernel<<<(waves * 64 + 255) / 256, 256, 0, stream>>>(
            x, sv, xh, xl, sh, sl, xnorm, svnorm);
    }
    {   // a split + padded svnorm + T zero
        prep_a<<<(16 * SPAD + 255) / 256, 256, 0, stream>>>(
            a, svnorm, ahp, alp, svnp, T);
    }
    {   // swapped GEMM + PV-MFMA reduce, sv-half split
        dim3 grid(N / 128, C, 2);
        svc_gemm<<<grid, 256, 0, stream>>>(xh, xl, sh, sl, ahp, alp,
                                           xnorm, svnp, T);
    }
    {   // voting
        vote_kernel<<<N / 256, 256, 0, stream>>>(T, b, out);
    }
}

// Round 5
// 168.128 us; speedup vs baseline: 1.2040x; 1.2040x over previous
//
#include <hip/hip_runtime.h>
#include <hip/hip_fp16.h>
#include <cmath>

// SVC_63737314673237 round 8: revert to verified R5 structure + ONE change:
// conflict-free LDS K-slot hash.
// R7 post-mortem: bundled z-split (bad tail math) + global-atomic epilogue
// (46MB HBM write-through, block-retirement stretch) + raw-barrier rework
// regressed 22%. Full revert to R5 (105us GEMM / 167.7 total).
// R8's single change: the XOR slot perm f(row)=row&3 puts rows {0,4,8,12}
// of each 16-lane read group in the SAME 4-bank group -> 4-way conflict
// (1.58x DS read cost, 7.99M conflict cycles). f(row)=(row>>1)&3 spreads
// the 16 rows over all 8 bank groups exactly 2x -> 2-way aliasing = free.
// Applied identically on stage-source (sg) and both read offsets.

#define GAMMA 0.01f
constexpr int N  = 8192;
constexpr int D  = 256;
constexpr int S  = 5000;
constexpr int C  = 10;
constexpr int NV = 500;
constexpr int R  = 9;     // C-1
constexpr int SPAD = 5120; // 10 classes x 512 padded cols

typedef _Float16 f16x8 __attribute__((ext_vector_type(8)));
typedef _Float16 f16x4 __attribute__((ext_vector_type(4)));
typedef float    f32x4 __attribute__((ext_vector_type(4)));

__device__ __forceinline__ void gload16(const void* g, void* l) {
    __builtin_amdgcn_global_load_lds(
        (const __attribute__((address_space(1))) void*)g,
        (__attribute__((address_space(3))) void*)l, 16, 0, 0);
}

// ---------------- fused split + norms: one wave per row ---------------------
__global__ __launch_bounds__(256) void prep_kernel(const float* __restrict__ x,
                                                   const float* __restrict__ sv,
                                                   _Float16* __restrict__ xh,
                                                   _Float16* __restrict__ xl,
                                                   _Float16* __restrict__ sh,
                                                   _Float16* __restrict__ sl,
                                                   float* __restrict__ xn,
                                                   float* __restrict__ svn) {
    int gid  = blockIdx.x * blockDim.x + threadIdx.x;
    int wid  = gid >> 6;
    int lane = gid & 63;
    if (wid >= N + S) return;
    bool isx = wid < N;
    int  r   = isx ? wid : wid - N;
    const float* row = isx ? (x + (size_t)r * D) : (sv + (size_t)r * D);
    float4 v = reinterpret_cast<const float4*>(row)[lane];
    float s = v.x * v.x + v.y * v.y + v.z * v.z + v.w * v.w;
#pragma unroll
    for (int off = 32; off > 0; off >>= 1) s += __shfl_xor(s, off, 64);
    float vv[4] = {v.x, v.y, v.z, v.w};
    f16x4 h, l;
#pragma unroll
    for (int k = 0; k < 4; ++k) {
        _Float16 hi = (_Float16)vv[k];
        h[k] = hi;
        l[k] = (_Float16)((vv[k] - (float)hi) * 4096.0f);
    }
    size_t o = (size_t)r * D + lane * 4;
    *(f16x4*)((isx ? xh : sh) + o) = h;
    *(f16x4*)((isx ? xl : sl) + o) = l;
    if (lane == 0) (isx ? xn : svn)[r] = s;
}

// ---------------- a split + padded svnorm -----------------------------------
__global__ __launch_bounds__(256) void prep_a(const float* __restrict__ a,
                                              const float* __restrict__ svn,
                                              _Float16* __restrict__ ah,
                                              _Float16* __restrict__ al,
                                              float* __restrict__ svnp) {
    int idx = blockIdx.x * 256 + threadIdx.x;
    if (idx >= 16 * SPAD) return;
    int r = idx / SPAD, col = idx - r * SPAD;
    int cls = col >> 9, j = col & 511;
    int s = cls * NV + ((j < NV) ? j : NV - 1);
    float av = (r < R && j < NV) ? a[(size_t)r * S + s] : 0.0f;
    _Float16 h = (_Float16)av;
    ah[idx] = h;
    al[idx] = (_Float16)((av - (float)h) * 4096.0f);
    if (r == 0) svnp[col] = svn[s];
}

// ---------------- swapped split-MFMA GEMM + exp + PV-MFMA reduce ------------
// grid: (128 row tiles, 10 classes). block 256 = 4 waves (wm,wn 2x2).
// wave tile: 64 sv x 32 n = 4x2 mfma tiles (16x16x32). 32 phases =
// 4 sv-chunks x 8 kb; gload_lds DMA double-buffer, 1 barrier/phase.
__global__ __launch_bounds__(256, 3) void svc_gemm(const _Float16* __restrict__ xh,
                                                   const _Float16* __restrict__ xl,
                                                   const _Float16* __restrict__ sh,
                                                   const _Float16* __restrict__ sl,
                                                   const _Float16* __restrict__ ahp,
                                                   const _Float16* __restrict__ alp,
                                                   const float* __restrict__ xnorm,
                                                   const float* __restrict__ svnp,
                                                   float* __restrict__ T) {
    __shared__ _Float16 SVs[2][2][128 * 32];  // 32KB: M-operand (sv rows)
    __shared__ _Float16 Xs[2][2][64 * 32];    // 16KB: N-operand (x rows)

    const int tid  = threadIdx.x;
    const int n0   = blockIdx.x * 64;
    const int cls  = blockIdx.y;
    const int w    = tid >> 6;
    const int lane = tid & 63;
    const int wm   = w >> 1;   // splits 128 m
    const int wn   = w & 1;    // splits 64 n
    const int lx   = lane & 15;
    const int quad = lane >> 4;

    // x-norms: n = wn*32 + nt*16 + lx (fixed per lane)
    float xnr[2];
#pragma unroll
    for (int nt = 0; nt < 2; ++nt)
        xnr[nt] = xnorm[n0 + wn * 32 + nt * 16 + lx];

    // fragment read offsets (f16 units), inverse of staged K-slot perm.
    // f(row) = (row>>1)&3: conflict-free (2-way only) across each 16-lane
    // read group -- R5's f(row)=row&3 was a 4-way conflict.
    int svoff[4], xoff[2];
#pragma unroll
    for (int mt = 0; mt < 4; ++mt) {
        int row = wm * 64 + mt * 16 + lx;
        svoff[mt] = row * 32 + ((quad - (row >> 1)) & 3) * 8;
    }
#pragma unroll
    for (int nt = 0; nt < 2; ++nt) {
        int row = wn * 32 + nt * 16 + lx;
        xoff[nt] = row * 32 + ((quad - (row >> 1)) & 3) * 8;
    }

    // staging: linear LDS dest (wave-uniform base + lane*16B), K-slot perm
    // on the GLOBAL source address. Position p of row r holds global slot
    // (p + f(r))&3, f(r) = (r>>1)&3. Note f(arow+64) == f(arow) (64>>1 = 32,
    // 32&3 == 0), so one sg serves both B row-halves.
    const int arow = tid >> 2, ag = tid & 3;
    const int sg   = (ag + (arow >> 1)) & 3;
    const int segend = cls * NV + NV - 1;
    const int ldsw = w * 512;

    auto stage = [&](int ph, int buf) {
        const int ch = ph >> 3, kb = ph & 7;
        const size_t koff = (size_t)(kb * 32 + sg * 8);
        const size_t goX  = (size_t)(n0 + arow) * D + koff;
        gload16(xh + goX, &Xs[buf][0][ldsw]);
        gload16(xl + goX, &Xs[buf][1][ldsw]);
        const int svbase = cls * NV + ch * 128;
        int svr0 = svbase + arow;      if (svr0 > segend) svr0 = segend;
        int svr1 = svbase + arow + 64; if (svr1 > segend) svr1 = segend;
        const size_t go0 = (size_t)svr0 * D + koff;
        const size_t go1 = (size_t)svr1 * D + koff;
        gload16(sh + go0, &SVs[buf][0][ldsw]);
        gload16(sl + go0, &SVs[buf][1][ldsw]);
        gload16(sh + go1, &SVs[buf][0][2048 + ldsw]);
        gload16(sl + go1, &SVs[buf][1][2048 + ldsw]);
    };

    f32x4 accM[4][2], accC[4][2];      // first-GEMM tiles [mt][nt]
#pragma unroll
    for (int mt = 0; mt < 4; ++mt)
#pragma unroll
        for (int nt = 0; nt < 2; ++nt) {
            accM[mt][nt] = (f32x4){0.f, 0.f, 0.f, 0.f};
            accC[mt][nt] = (f32x4){0.f, 0.f, 0.f, 0.f};
        }
    f32x4 accO[2], accOC[2];           // PV output tiles [nt] (r x n)
#pragma unroll
    for (int nt = 0; nt < 2; ++nt) {
        accO[nt]  = (f32x4){0.f, 0.f, 0.f, 0.f};
        accOC[nt] = (f32x4){0.f, 0.f, 0.f, 0.f};
    }

    stage(0, 0);
    __syncthreads();

    for (int ph = 0; ph < 32; ++ph) {
        const int buf = ph & 1;
        if (ph < 31) stage(ph + 1, buf ^ 1);   // DMA overlaps MFMAs

        f16x8 Am[2][4], Bx[2][2];
#pragma unroll
        for (int mt = 0; mt < 4; ++mt) {
            Am[0][mt] = *(const f16x8*)(&SVs[buf][0][svoff[mt]]);
            Am[1][mt] = *(const f16x8*)(&SVs[buf][1][svoff[mt]]);
        }
#pragma unroll
        for (int nt = 0; nt < 2; ++nt) {
            Bx[0][nt] = *(const f16x8*)(&Xs[buf][0][xoff[nt]]);
            Bx[1][nt] = *(const f16x8*)(&Xs[buf][1][xoff[nt]]);
        }
#pragma unroll
        for (int mt = 0; mt < 4; ++mt)
#pragma unroll
            for (int nt = 0; nt < 2; ++nt) {
                accM[mt][nt] = __builtin_amdgcn_mfma_f32_16x16x32_f16(
                    Am[0][mt], Bx[0][nt], accM[mt][nt], 0, 0, 0);
                accC[mt][nt] = __builtin_amdgcn_mfma_f32_16x16x32_f16(
                    Am[0][mt], Bx[1][nt], accC[mt][nt], 0, 0, 0);
                accC[mt][nt] = __builtin_amdgcn_mfma_f32_16x16x32_f16(
                    Am[1][mt], Bx[0][nt], accC[mt][nt], 0, 0, 0);
            }

        __syncthreads();   // vmcnt(0): next buf's DMA landed

        if ((ph & 7) == 7) {   // chunk done: exp + PV-MFMA reduce (no DS!)
            const int ch = ph >> 3;
            const int mbase = cls * 512 + ch * 128 + wm * 64;
#pragma unroll
            for (int mt = 0; mt < 4; ++mt) {
                const size_t ao = (size_t)lx * SPAD + mbase + mt * 16 + quad * 4;
                f16x4 afh = *(const f16x4*)(ahp + ao);   // A-frag: a[r=lx, k]
                f16x4 afl = *(const f16x4*)(alp + ao);
                float4 sn4 = *(const float4*)(svnp + mbase + mt * 16 + quad * 4);
#pragma unroll
                for (int nt = 0; nt < 2; ++nt) {
                    f16x4 bh, bl;   // B-frag: kv[k = quad*4+reg, col = lx]
#pragma unroll
                    for (int reg = 0; reg < 4; ++reg) {
                        float dot = accM[mt][nt][reg]
                                  + accC[mt][nt][reg] * (1.0f / 4096.0f);
                        float e  = fmaf(2.0f * GAMMA, dot,
                                        -GAMMA * (xnr[nt] + sn4[reg]));
                        float kv = __expf(e);
                        _Float16 h = (_Float16)kv;
                        bh[reg] = h;
                        bl[reg] = (_Float16)((kv - (float)h) * 4096.0f);
                    }
                    accO[nt]  = __builtin_amdgcn_mfma_f32_16x16x16f16(
                        afh, bh, accO[nt], 0, 0, 0);
                    accOC[nt] = __builtin_amdgcn_mfma_f32_16x16x16f16(
                        afh, bl, accOC[nt], 0, 0, 0);
                    accOC[nt] = __builtin_amdgcn_mfma_f32_16x16x16f16(
                        afl, bh, accOC[nt], 0, 0, 0);
                    accM[mt][nt] = (f32x4){0.f, 0.f, 0.f, 0.f};
                    accC[mt][nt] = (f32x4){0.f, 0.f, 0.f, 0.f};
                }
            }
        }
    }

    // cross-wm reduce via 8KB of reused SVs space, then store T.
    // accO tile layout: row r = quad*4+reg, col n = wn*32 + nt*16 + lx.
    float* scr = (float*)&SVs[0][0][0];
    if (wm == 0) {
#pragma unroll
        for (int nt = 0; nt < 2; ++nt)
#pragma unroll
            for (int reg = 0; reg < 4; ++reg) {
                int base = ((wn * 2 + nt) * 2) * 256 + (quad * 4 + reg) * 16 + lx;
                scr[base]       = accO[nt][reg];
                scr[base + 256] = accOC[nt][reg];
            }
    }
    __syncthreads();
    if (wm == 1) {
#pragma unroll
        for (int nt = 0; nt < 2; ++nt)
#pragma unroll
            for (int reg = 0; reg < 4; ++reg) {
                int r = quad * 4 + reg;
                if (r < R) {
                    int base = ((wn * 2 + nt) * 2) * 256 + r * 16 + lx;
                    float o  = accO[nt][reg]  + scr[base];
                    float oc = accOC[nt][reg] + scr[base + 256];
                    int n = n0 + wn * 32 + nt * 16 + lx;
                    T[(size_t)n * 90 + r * 10 + cls] = o + oc * (1.0f / 4096.0f);
                }
            }
    }
}

// ---------------- pairwise voting + argmax ----------------------------------
__global__ __launch_bounds__(256) void vote_kernel(const float* __restrict__ T,
                                                   const float* __restrict__ b,
                                                   int* __restrict__ out) {
    int n = blockIdx.x * blockDim.x + threadIdx.x;
    if (n >= N) return;
    const float* Tn = T + (size_t)n * 90;
    float tv[90];
#pragma unroll
    for (int i = 0; i < 90; ++i) tv[i] = Tn[i];
    int counts[C];
#pragma unroll
    for (int k = 0; k < C; ++k) counts[k] = 0;
    int p = 0;
#pragma unroll
    for (int i = 0; i < C; ++i) {
#pragma unroll
        for (int j = i + 1; j < C; ++j) {
            float c = tv[i * 10 + j] + tv[(j - 1) * 10 + i] + b[p];
            if (c > 0.f) counts[i]++; else counts[j]++;
            ++p;
        }
    }
    int best = 0;
#pragma unroll
    for (int k = 1; k < C; ++k)
        if (counts[k] > counts[best]) best = k;
    out[n]     = best;
    out[N + n] = best;
}

extern "C" void kernel_launch(void* const* d_in, const int* in_sizes, int n_in,
                              void* d_out, int out_size, void* d_ws, size_t ws_size,
                              hipStream_t stream) {
    const float* x  = (const float*)d_in[0];   // [8192,256]
    const float* sv = (const float*)d_in[1];   // [5000,256]
    const float* a  = (const float*)d_in[2];   // [9,5000]
    const float* b  = (const float*)d_in[3];   // [45]
    int* out = (int*)d_out;

    char* wp = (char*)d_ws;
    _Float16* xh = (_Float16*)wp;  wp += (size_t)N * D * 2;
    _Float16* xl = (_Float16*)wp;  wp += (size_t)N * D * 2;
    _Float16* sh = (_Float16*)wp;  wp += (size_t)S * D * 2;
    _Float16* sl = (_Float16*)wp;  wp += (size_t)S * D * 2;
    float* xnorm  = (float*)wp;    wp += (size_t)N * 4;
    float* svnorm = (float*)wp;    wp += (size_t)S * 4;
    _Float16* ahp = (_Float16*)wp; wp += (size_t)16 * SPAD * 2;
    _Float16* alp = (_Float16*)wp; wp += (size_t)16 * SPAD * 2;
    float* svnp   = (float*)wp;    wp += (size_t)SPAD * 4;
    float* T      = (float*)wp;

    {   // fused split + norms: one wave per row
        int waves = N + S;
        prep_kernel<<<(waves * 64 + 255) / 256, 256, 0, stream>>>(
            x, sv, xh, xl, sh, sl, xnorm, svnorm);
    }
    {   // a split + padded svnorm (needs svnorm: stream-ordered after prep)
        prep_a<<<(16 * SPAD + 255) / 256, 256, 0, stream>>>(
            a, svnorm, ahp, alp, svnp);
    }
    {   // swapped GEMM + PV-MFMA reduce
        dim3 grid(N / 64, C);
        svc_gemm<<<grid, 256, 0, stream>>>(xh, xl, sh, sl, ahp, alp,
                                           xnorm, svnp, T);
    }
    {   // voting
        vote_kernel<<<N / 256, 256, 0, stream>>>(T, b, out);
    }
}

// Round 7
// 166.433 us; speedup vs baseline: 1.2162x; 1.0102x over previous
//
#include <hip/hip_runtime.h>
#include <hip/hip_fp16.h>
#include <cmath>

// SVC_63737314673237 round 9 (resubmit; R6 bench died to infra "container
// failed twice" before dispatch). Attack the constant ~63us non-GEMM cost.
// Evidence: total - svc_gemm = 61,57,62,67,65.5us across R0-R8 (invariant
// under all GEMM changes). vote_kernel read T[n*90+i] = 64-segment gather
// per load (90x per thread) -> tens of us. Changes vs R8:
//  (1) T transposed to [90][N]: GEMM epilogue stores 64B-contiguous per
//      16-lane group; vote loads fully coalesced (1KB/wave/load).
//  (2) prep_a folded into prep (a-split needs only `a`; svnp written by
//      the sv-row waves that hold the norm in-register) -> 3 launches.
// GEMM core byte-identical to verified R8 (conflict-free (row>>1)&3 hash,
// 102.6us, conflicts 123K) except the single T-store line.

#define GAMMA 0.01f
constexpr int N  = 8192;
constexpr int D  = 256;
constexpr int S  = 5000;
constexpr int C  = 10;
constexpr int NV = 500;
constexpr int R  = 9;     // C-1
constexpr int SPAD = 5120; // 10 classes x 512 padded cols

constexpr int ROW_BLOCKS = (N + S) / 4;       // 3298 (13192 row-waves, 4/block)
constexpr int A_BLOCKS   = (16 * SPAD) / 256; // 320

typedef _Float16 f16x8 __attribute__((ext_vector_type(8)));
typedef _Float16 f16x4 __attribute__((ext_vector_type(4)));
typedef float    f32x4 __attribute__((ext_vector_type(4)));

__device__ __forceinline__ void gload16(const void* g, void* l) {
    __builtin_amdgcn_global_load_lds(
        (const __attribute__((address_space(1))) void*)g,
        (__attribute__((address_space(3))) void*)l, 16, 0, 0);
}

// ---------------- fused split + norms + a-split + svnp ----------------------
// blocks [0, ROW_BLOCKS): one wave per x/sv row (split + norm; sv waves also
// write their svnp slot, clamped pad cols by the j==NV-1 wave).
// blocks [ROW_BLOCKS, ROW_BLOCKS+A_BLOCKS): a -> ah/al zero-padded [16][SPAD].
__global__ __launch_bounds__(256) void prep_kernel(const float* __restrict__ x,
                                                   const float* __restrict__ sv,
                                                   const float* __restrict__ a,
                                                   _Float16* __restrict__ xh,
                                                   _Float16* __restrict__ xl,
                                                   _Float16* __restrict__ sh,
                                                   _Float16* __restrict__ sl,
                                                   float* __restrict__ xn,
                                                   _Float16* __restrict__ ah,
                                                   _Float16* __restrict__ al,
                                                   float* __restrict__ svnp) {
    if (blockIdx.x >= ROW_BLOCKS) {
        int idx = (blockIdx.x - ROW_BLOCKS) * 256 + threadIdx.x;
        int r = idx / SPAD, col = idx - r * SPAD;
        int cls = col >> 9, j = col & 511;
        int s = cls * NV + ((j < NV) ? j : NV - 1);
        float av = (r < R && j < NV) ? a[(size_t)r * S + s] : 0.0f;
        _Float16 h = (_Float16)av;
        ah[idx] = h;
        al[idx] = (_Float16)((av - (float)h) * 4096.0f);
        return;
    }
    int gid  = blockIdx.x * blockDim.x + threadIdx.x;
    int wid  = gid >> 6;
    int lane = gid & 63;
    bool isx = wid < N;
    int  r   = isx ? wid : wid - N;
    const float* row = isx ? (x + (size_t)r * D) : (sv + (size_t)r * D);
    float4 v = reinterpret_cast<const float4*>(row)[lane];
    float s = v.x * v.x + v.y * v.y + v.z * v.z + v.w * v.w;
#pragma unroll
    for (int off = 32; off > 0; off >>= 1) s += __shfl_xor(s, off, 64);
    float vv[4] = {v.x, v.y, v.z, v.w};
    f16x4 h, l;
#pragma unroll
    for (int k = 0; k < 4; ++k) {
        _Float16 hi = (_Float16)vv[k];
        h[k] = hi;
        l[k] = (_Float16)((vv[k] - (float)hi) * 4096.0f);
    }
    size_t o = (size_t)r * D + lane * 4;
    *(f16x4*)((isx ? xh : sh) + o) = h;
    *(f16x4*)((isx ? xl : sl) + o) = l;
    if (lane == 0) {
        if (isx) {
            xn[r] = s;
        } else {
            int cls = r / NV, j = r - cls * NV;
            svnp[cls * 512 + j] = s;
            if (j == NV - 1)                      // fill pad cols 500..511
                for (int p = NV; p < 512; ++p) svnp[cls * 512 + p] = s;
        }
    }
}

// ---------------- swapped split-MFMA GEMM + exp + PV-MFMA reduce ------------
// grid: (128 row tiles, 10 classes). block 256 = 4 waves (wm,wn 2x2).
// wave tile: 64 sv x 32 n = 4x2 mfma tiles (16x16x32). 32 phases =
// 4 sv-chunks x 8 kb; gload_lds DMA double-buffer, 1 barrier/phase.
// Conflict-free K-slot hash f(row)=(row>>1)&3 (R8, verified).
__global__ __launch_bounds__(256, 3) void svc_gemm(const _Float16* __restrict__ xh,
                                                   const _Float16* __restrict__ xl,
                                                   const _Float16* __restrict__ sh,
                                                   const _Float16* __restrict__ sl,
                                                   const _Float16* __restrict__ ahp,
                                                   const _Float16* __restrict__ alp,
                                                   const float* __restrict__ xnorm,
                                                   const float* __restrict__ svnp,
                                                   float* __restrict__ T) {
    __shared__ _Float16 SVs[2][2][128 * 32];  // 32KB: M-operand (sv rows)
    __shared__ _Float16 Xs[2][2][64 * 32];    // 16KB: N-operand (x rows)

    const int tid  = threadIdx.x;
    const int n0   = blockIdx.x * 64;
    const int cls  = blockIdx.y;
    const int w    = tid >> 6;
    const int lane = tid & 63;
    const int wm   = w >> 1;   // splits 128 m
    const int wn   = w & 1;    // splits 64 n
    const int lx   = lane & 15;
    const int quad = lane >> 4;

    float xnr[2];
#pragma unroll
    for (int nt = 0; nt < 2; ++nt)
        xnr[nt] = xnorm[n0 + wn * 32 + nt * 16 + lx];

    int svoff[4], xoff[2];
#pragma unroll
    for (int mt = 0; mt < 4; ++mt) {
        int row = wm * 64 + mt * 16 + lx;
        svoff[mt] = row * 32 + ((quad - (row >> 1)) & 3) * 8;
    }
#pragma unroll
    for (int nt = 0; nt < 2; ++nt) {
        int row = wn * 32 + nt * 16 + lx;
        xoff[nt] = row * 32 + ((quad - (row >> 1)) & 3) * 8;
    }

    const int arow = tid >> 2, ag = tid & 3;
    const int sg   = (ag + (arow >> 1)) & 3;
    const int segend = cls * NV + NV - 1;
    const int ldsw = w * 512;

    auto stage = [&](int ph, int buf) {
        const int ch = ph >> 3, kb = ph & 7;
        const size_t koff = (size_t)(kb * 32 + sg * 8);
        const size_t goX  = (size_t)(n0 + arow) * D + koff;
        gload16(xh + goX, &Xs[buf][0][ldsw]);
        gload16(xl + goX, &Xs[buf][1][ldsw]);
        const int svbase = cls * NV + ch * 128;
        int svr0 = svbase + arow;      if (svr0 > segend) svr0 = segend;
        int svr1 = svbase + arow + 64; if (svr1 > segend) svr1 = segend;
        const size_t go0 = (size_t)svr0 * D + koff;
        const size_t go1 = (size_t)svr1 * D + koff;
        gload16(sh + go0, &SVs[buf][0][ldsw]);
        gload16(sl + go0, &SVs[buf][1][ldsw]);
        gload16(sh + go1, &SVs[buf][0][2048 + ldsw]);
        gload16(sl + go1, &SVs[buf][1][2048 + ldsw]);
    };

    f32x4 accM[4][2], accC[4][2];      // first-GEMM tiles [mt][nt]
#pragma unroll
    for (int mt = 0; mt < 4; ++mt)
#pragma unroll
        for (int nt = 0; nt < 2; ++nt) {
            accM[mt][nt] = (f32x4){0.f, 0.f, 0.f, 0.f};
            accC[mt][nt] = (f32x4){0.f, 0.f, 0.f, 0.f};
        }
    f32x4 accO[2], accOC[2];           // PV output tiles [nt] (r x n)
#pragma unroll
    for (int nt = 0; nt < 2; ++nt) {
        accO[nt]  = (f32x4){0.f, 0.f, 0.f, 0.f};
        accOC[nt] = (f32x4){0.f, 0.f, 0.f, 0.f};
    }

    stage(0, 0);
    __syncthreads();

    for (int ph = 0; ph < 32; ++ph) {
        const int buf = ph & 1;
        if (ph < 31) stage(ph + 1, buf ^ 1);   // DMA overlaps MFMAs

        f16x8 Am[2][4], Bx[2][2];
#pragma unroll
        for (int mt = 0; mt < 4; ++mt) {
            Am[0][mt] = *(const f16x8*)(&SVs[buf][0][svoff[mt]]);
            Am[1][mt] = *(const f16x8*)(&SVs[buf][1][svoff[mt]]);
        }
#pragma unroll
        for (int nt = 0; nt < 2; ++nt) {
            Bx[0][nt] = *(const f16x8*)(&Xs[buf][0][xoff[nt]]);
            Bx[1][nt] = *(const f16x8*)(&Xs[buf][1][xoff[nt]]);
        }
#pragma unroll
        for (int mt = 0; mt < 4; ++mt)
#pragma unroll
            for (int nt = 0; nt < 2; ++nt) {
                accM[mt][nt] = __builtin_amdgcn_mfma_f32_16x16x32_f16(
                    Am[0][mt], Bx[0][nt], accM[mt][nt], 0, 0, 0);
                accC[mt][nt] = __builtin_amdgcn_mfma_f32_16x16x32_f16(
                    Am[0][mt], Bx[1][nt], accC[mt][nt], 0, 0, 0);
                accC[mt][nt] = __builtin_amdgcn_mfma_f32_16x16x32_f16(
                    Am[1][mt], Bx[0][nt], accC[mt][nt], 0, 0, 0);
            }

        __syncthreads();   // vmcnt(0): next buf's DMA landed

        if ((ph & 7) == 7) {   // chunk done: exp + PV-MFMA reduce (no DS!)
            const int ch = ph >> 3;
            const int mbase = cls * 512 + ch * 128 + wm * 64;
#pragma unroll
            for (int mt = 0; mt < 4; ++mt) {
                const size_t ao = (size_t)lx * SPAD + mbase + mt * 16 + quad * 4;
                f16x4 afh = *(const f16x4*)(ahp + ao);   // A-frag: a[r=lx, k]
                f16x4 afl = *(const f16x4*)(alp + ao);
                float4 sn4 = *(const float4*)(svnp + mbase + mt * 16 + quad * 4);
#pragma unroll
                for (int nt = 0; nt < 2; ++nt) {
                    f16x4 bh, bl;   // B-frag: kv[k = quad*4+reg, col = lx]
#pragma unroll
                    for (int reg = 0; reg < 4; ++reg) {
                        float dot = accM[mt][nt][reg]
                                  + accC[mt][nt][reg] * (1.0f / 4096.0f);
                        float e  = fmaf(2.0f * GAMMA, dot,
                                        -GAMMA * (xnr[nt] + sn4[reg]));
                        float kv = __expf(e);
                        _Float16 h = (_Float16)kv;
                        bh[reg] = h;
                        bl[reg] = (_Float16)((kv - (float)h) * 4096.0f);
                    }
                    accO[nt]  = __builtin_amdgcn_mfma_f32_16x16x16f16(
                        afh, bh, accO[nt], 0, 0, 0);
                    accOC[nt] = __builtin_amdgcn_mfma_f32_16x16x16f16(
                        afh, bl, accOC[nt], 0, 0, 0);
                    accOC[nt] = __builtin_amdgcn_mfma_f32_16x16x16f16(
                        afl, bh, accOC[nt], 0, 0, 0);
                    accM[mt][nt] = (f32x4){0.f, 0.f, 0.f, 0.f};
                    accC[mt][nt] = (f32x4){0.f, 0.f, 0.f, 0.f};
                }
            }
        }
    }

    // cross-wm reduce via 8KB of reused SVs space, then store T (transposed
    // [90][N] layout: 16 lanes -> 64B contiguous, coalesced).
    float* scr = (float*)&SVs[0][0][0];
    if (wm == 0) {
#pragma unroll
        for (int nt = 0; nt < 2; ++nt)
#pragma unroll
            for (int reg = 0; reg < 4; ++reg) {
                int base = ((wn * 2 + nt) * 2) * 256 + (quad * 4 + reg) * 16 + lx;
                scr[base]       = accO[nt][reg];
                scr[base + 256] = accOC[nt][reg];
            }
    }
    __syncthreads();
    if (wm == 1) {
#pragma unroll
        for (int nt = 0; nt < 2; ++nt)
#pragma unroll
            for (int reg = 0; reg < 4; ++reg) {
                int r = quad * 4 + reg;
                if (r < R) {
                    int base = ((wn * 2 + nt) * 2) * 256 + r * 16 + lx;
                    float o  = accO[nt][reg]  + scr[base];
                    float oc = accOC[nt][reg] + scr[base + 256];
                    int n = n0 + wn * 32 + nt * 16 + lx;
                    T[(size_t)(r * 10 + cls) * N + n] = o + oc * (1.0f / 4096.0f);
                }
            }
    }
}

// ---------------- pairwise voting + argmax ----------------------------------
// T is [90][N]: every load below is a coalesced 1KB/wave read.
__global__ __launch_bounds__(256) void vote_kernel(const float* __restrict__ T,
                                                   const float* __restrict__ b,
                                                   int* __restrict__ out) {
    int n = blockIdx.x * blockDim.x + threadIdx.x;
    if (n >= N) return;
    float tv[90];
#pragma unroll
    for (int i = 0; i < 90; ++i) tv[i] = T[(size_t)i * N + n];
    int counts[C];
#pragma unroll
    for (int k = 0; k < C; ++k) counts[k] = 0;
    int p = 0;
#pragma unroll
    for (int i = 0; i < C; ++i) {
#pragma unroll
        for (int j = i + 1; j < C; ++j) {
            float c = tv[i * 10 + j] + tv[(j - 1) * 10 + i] + b[p];
            if (c > 0.f) counts[i]++; else counts[j]++;
            ++p;
        }
    }
    int best = 0;
#pragma unroll
    for (int k = 1; k < C; ++k)
        if (counts[k] > counts[best]) best = k;
    out[n]     = best;
    out[N + n] = best;
}

extern "C" void kernel_launch(void* const* d_in, const int* in_sizes, int n_in,
                              void* d_out, int out_size, void* d_ws, size_t ws_size,
                              hipStream_t stream) {
    const float* x  = (const float*)d_in[0];   // [8192,256]
    const float* sv = (const float*)d_in[1];   // [5000,256]
    const float* a  = (const float*)d_in[2];   // [9,5000]
    const float* b  = (const float*)d_in[3];   // [45]
    int* out = (int*)d_out;

    char* wp = (char*)d_ws;
    _Float16* xh = (_Float16*)wp;  wp += (size_t)N * D * 2;
    _Float16* xl = (_Float16*)wp;  wp += (size_t)N * D * 2;
    _Float16* sh = (_Float16*)wp;  wp += (size_t)S * D * 2;
    _Float16* sl = (_Float16*)wp;  wp += (size_t)S * D * 2;
    float* xnorm  = (float*)wp;    wp += (size_t)N * 4;
    _Float16* ahp = (_Float16*)wp; wp += (size_t)16 * SPAD * 2;
    _Float16* alp = (_Float16*)wp; wp += (size_t)16 * SPAD * 2;
    float* svnp   = (float*)wp;    wp += (size_t)SPAD * 4;
    float* T      = (float*)wp;    // [90][N]

    {   // fused split + norms + a-split + svnp (one launch)
        prep_kernel<<<ROW_BLOCKS + A_BLOCKS, 256, 0, stream>>>(
            x, sv, a, xh, xl, sh, sl, xnorm, ahp, alp, svnp);
    }
    {   // swapped GEMM + PV-MFMA reduce
        dim3 grid(N / 64, C);
        svc_gemm<<<grid, 256, 0, stream>>>(xh, xl, sh, sl, ahp, alp,
                                           xnorm, svnp, T);
    }
    {   // voting
        vote_kernel<<<N / 256, 256, 0, stream>>>(T, b, out);
    }
}

// Round 8
// 164.628 us; speedup vs baseline: 1.2296x; 1.0110x over previous
//
#include <hip/hip_runtime.h>
#include <hip/hip_fp16.h>
#include <cmath>

// SVC_63737314673237 round 10: counted-vmcnt phase schedule (T3/T4+T5).
// R9 post-mortem: non-GEMM ~63us is fixed harness overhead (vote fix moved
// nothing); all slack is in svc_gemm (103.5us vs ~31us MFMA floor). Phase
// accounting: DS 768cy + MFMA 384cy per block-phase vs ~4600cy window ->
// ~50% stall = the __syncthreads vmcnt(0) draining stage(ph+1) issued only
// ~400cy earlier (m97-ceiling mechanism). R10: wait moves to phase TOP as
// vmcnt(6) (stage(ph) landed, stage(ph+1) stays in flight), raw s_barrier,
// frags+MFMAs(setprio-wrapped), then lgkmcnt(0)+raw barrier with NO vmcnt
// drain. Two barriers/phase (R7's 1-barrier variant raced: read-vs-DMA
// overwrite needs the bottom barrier). Everything else identical to R9
// (verified: conflict-free (row>>1)&3 hash, [90][N] T, fused prep).

#define GAMMA 0.01f
constexpr int N  = 8192;
constexpr int D  = 256;
constexpr int S  = 5000;
constexpr int C  = 10;
constexpr int NV = 500;
constexpr int R  = 9;     // C-1
constexpr int SPAD = 5120; // 10 classes x 512 padded cols

constexpr int ROW_BLOCKS = (N + S) / 4;       // 3298 (13192 row-waves, 4/block)
constexpr int A_BLOCKS   = (16 * SPAD) / 256; // 320

typedef _Float16 f16x8 __attribute__((ext_vector_type(8)));
typedef _Float16 f16x4 __attribute__((ext_vector_type(4)));
typedef float    f32x4 __attribute__((ext_vector_type(4)));

__device__ __forceinline__ void gload16(const void* g, void* l) {
    __builtin_amdgcn_global_load_lds(
        (const __attribute__((address_space(1))) void*)g,
        (__attribute__((address_space(3))) void*)l, 16, 0, 0);
}

// ---------------- fused split + norms + a-split + svnp ----------------------
__global__ __launch_bounds__(256) void prep_kernel(const float* __restrict__ x,
                                                   const float* __restrict__ sv,
                                                   const float* __restrict__ a,
                                                   _Float16* __restrict__ xh,
                                                   _Float16* __restrict__ xl,
                                                   _Float16* __restrict__ sh,
                                                   _Float16* __restrict__ sl,
                                                   float* __restrict__ xn,
                                                   _Float16* __restrict__ ah,
                                                   _Float16* __restrict__ al,
                                                   float* __restrict__ svnp) {
    if (blockIdx.x >= ROW_BLOCKS) {
        int idx = (blockIdx.x - ROW_BLOCKS) * 256 + threadIdx.x;
        int r = idx / SPAD, col = idx - r * SPAD;
        int cls = col >> 9, j = col & 511;
        int s = cls * NV + ((j < NV) ? j : NV - 1);
        float av = (r < R && j < NV) ? a[(size_t)r * S + s] : 0.0f;
        _Float16 h = (_Float16)av;
        ah[idx] = h;
        al[idx] = (_Float16)((av - (float)h) * 4096.0f);
        return;
    }
    int gid  = blockIdx.x * blockDim.x + threadIdx.x;
    int wid  = gid >> 6;
    int lane = gid & 63;
    bool isx = wid < N;
    int  r   = isx ? wid : wid - N;
    const float* row = isx ? (x + (size_t)r * D) : (sv + (size_t)r * D);
    float4 v = reinterpret_cast<const float4*>(row)[lane];
    float s = v.x * v.x + v.y * v.y + v.z * v.z + v.w * v.w;
#pragma unroll
    for (int off = 32; off > 0; off >>= 1) s += __shfl_xor(s, off, 64);
    float vv[4] = {v.x, v.y, v.z, v.w};
    f16x4 h, l;
#pragma unroll
    for (int k = 0; k < 4; ++k) {
        _Float16 hi = (_Float16)vv[k];
        h[k] = hi;
        l[k] = (_Float16)((vv[k] - (float)hi) * 4096.0f);
    }
    size_t o = (size_t)r * D + lane * 4;
    *(f16x4*)((isx ? xh : sh) + o) = h;
    *(f16x4*)((isx ? xl : sl) + o) = l;
    if (lane == 0) {
        if (isx) {
            xn[r] = s;
        } else {
            int cls = r / NV, j = r - cls * NV;
            svnp[cls * 512 + j] = s;
            if (j == NV - 1)                      // fill pad cols 500..511
                for (int p = NV; p < 512; ++p) svnp[cls * 512 + p] = s;
        }
    }
}

// ---------------- swapped split-MFMA GEMM + exp + PV-MFMA reduce ------------
// grid: (128 row tiles, 10 classes). block 256 = 4 waves (wm,wn 2x2).
// wave tile: 64 sv x 32 n = 4x2 mfma tiles (16x16x32). 32 phases =
// 4 sv-chunks x 8 kb; gload_lds DMA double-buffer.
// Phase schedule (R10): {issue stage(ph+1); vmcnt(6); s_barrier; ds_reads;
// setprio(1) MFMAs setprio(0); [epilogue]; lgkmcnt(0); s_barrier} -- the
// prefetch stays in flight across the bottom barrier (never vmcnt(0) in
// the main loop).
__global__ __launch_bounds__(256, 3) void svc_gemm(const _Float16* __restrict__ xh,
                                                   const _Float16* __restrict__ xl,
                                                   const _Float16* __restrict__ sh,
                                                   const _Float16* __restrict__ sl,
                                                   const _Float16* __restrict__ ahp,
                                                   const _Float16* __restrict__ alp,
                                                   const float* __restrict__ xnorm,
                                                   const float* __restrict__ svnp,
                                                   float* __restrict__ T) {
    __shared__ _Float16 SVs[2][2][128 * 32];  // 32KB: M-operand (sv rows)
    __shared__ _Float16 Xs[2][2][64 * 32];    // 16KB: N-operand (x rows)

    const int tid  = threadIdx.x;
    const int n0   = blockIdx.x * 64;
    const int cls  = blockIdx.y;
    const int w    = tid >> 6;
    const int lane = tid & 63;
    const int wm   = w >> 1;   // splits 128 m
    const int wn   = w & 1;    // splits 64 n
    const int lx   = lane & 15;
    const int quad = lane >> 4;

    float xnr[2];
#pragma unroll
    for (int nt = 0; nt < 2; ++nt)
        xnr[nt] = xnorm[n0 + wn * 32 + nt * 16 + lx];

    int svoff[4], xoff[2];
#pragma unroll
    for (int mt = 0; mt < 4; ++mt) {
        int row = wm * 64 + mt * 16 + lx;
        svoff[mt] = row * 32 + ((quad - (row >> 1)) & 3) * 8;
    }
#pragma unroll
    for (int nt = 0; nt < 2; ++nt) {
        int row = wn * 32 + nt * 16 + lx;
        xoff[nt] = row * 32 + ((quad - (row >> 1)) & 3) * 8;
    }

    const int arow = tid >> 2, ag = tid & 3;
    const int sg   = (ag + (arow >> 1)) & 3;
    const int segend = cls * NV + NV - 1;
    const int ldsw = w * 512;

    auto stage = [&](int ph, int buf) {
        const int ch = ph >> 3, kb = ph & 7;
        const size_t koff = (size_t)(kb * 32 + sg * 8);
        const size_t goX  = (size_t)(n0 + arow) * D + koff;
        gload16(xh + goX, &Xs[buf][0][ldsw]);
        gload16(xl + goX, &Xs[buf][1][ldsw]);
        const int svbase = cls * NV + ch * 128;
        int svr0 = svbase + arow;      if (svr0 > segend) svr0 = segend;
        int svr1 = svbase + arow + 64; if (svr1 > segend) svr1 = segend;
        const size_t go0 = (size_t)svr0 * D + koff;
        const size_t go1 = (size_t)svr1 * D + koff;
        gload16(sh + go0, &SVs[buf][0][ldsw]);
        gload16(sl + go0, &SVs[buf][1][ldsw]);
        gload16(sh + go1, &SVs[buf][0][2048 + ldsw]);
        gload16(sl + go1, &SVs[buf][1][2048 + ldsw]);
    };

    f32x4 accM[4][2], accC[4][2];      // first-GEMM tiles [mt][nt]
#pragma unroll
    for (int mt = 0; mt < 4; ++mt)
#pragma unroll
        for (int nt = 0; nt < 2; ++nt) {
            accM[mt][nt] = (f32x4){0.f, 0.f, 0.f, 0.f};
            accC[mt][nt] = (f32x4){0.f, 0.f, 0.f, 0.f};
        }
    f32x4 accO[2], accOC[2];           // PV output tiles [nt] (r x n)
#pragma unroll
    for (int nt = 0; nt < 2; ++nt) {
        accO[nt]  = (f32x4){0.f, 0.f, 0.f, 0.f};
        accOC[nt] = (f32x4){0.f, 0.f, 0.f, 0.f};
    }

    stage(0, 0);

    for (int ph = 0; ph < 32; ++ph) {
        const int buf = ph & 1;
        // -- phase top: issue next stage, then COUNTED drain of stage(ph).
        // vmcnt(6): the newest 6 (stage(ph+1)) stay in flight; everything
        // older (incl. stage(ph)) has landed. In-order retirement makes any
        // older stray loads (xnr, epilogue) harmless.
        if (ph < 31) {
            stage(ph + 1, buf ^ 1);
            asm volatile("s_waitcnt vmcnt(6)" ::: "memory");
        } else {
            asm volatile("s_waitcnt vmcnt(0)" ::: "memory");
        }
        __builtin_amdgcn_s_barrier();      // all waves' stage(ph) visible
        asm volatile("" ::: "memory");

        f16x8 Am[2][4], Bx[2][2];
#pragma unroll
        for (int mt = 0; mt < 4; ++mt) {
            Am[0][mt] = *(const f16x8*)(&SVs[buf][0][svoff[mt]]);
            Am[1][mt] = *(const f16x8*)(&SVs[buf][1][svoff[mt]]);
        }
#pragma unroll
        for (int nt = 0; nt < 2; ++nt) {
            Bx[0][nt] = *(const f16x8*)(&Xs[buf][0][xoff[nt]]);
            Bx[1][nt] = *(const f16x8*)(&Xs[buf][1][xoff[nt]]);
        }
        __builtin_amdgcn_s_setprio(1);
#pragma unroll
        for (int mt = 0; mt < 4; ++mt)
#pragma unroll
            for (int nt = 0; nt < 2; ++nt) {
                accM[mt][nt] = __builtin_amdgcn_mfma_f32_16x16x32_f16(
                    Am[0][mt], Bx[0][nt], accM[mt][nt], 0, 0, 0);
                accC[mt][nt] = __builtin_amdgcn_mfma_f32_16x16x32_f16(
                    Am[0][mt], Bx[1][nt], accC[mt][nt], 0, 0, 0);
                accC[mt][nt] = __builtin_amdgcn_mfma_f32_16x16x32_f16(
                    Am[1][mt], Bx[0][nt], accC[mt][nt], 0, 0, 0);
            }
        __builtin_amdgcn_s_setprio(0);

        if ((ph & 7) == 7) {   // chunk done: exp + PV-MFMA reduce (no DS)
            const int ch = ph >> 3;
            const int mbase = cls * 512 + ch * 128 + wm * 64;
#pragma unroll
            for (int mt = 0; mt < 4; ++mt) {
                const size_t ao = (size_t)lx * SPAD + mbase + mt * 16 + quad * 4;
                f16x4 afh = *(const f16x4*)(ahp + ao);   // A-frag: a[r=lx, k]
                f16x4 afl = *(const f16x4*)(alp + ao);
                float4 sn4 = *(const float4*)(svnp + mbase + mt * 16 + quad * 4);
#pragma unroll
                for (int nt = 0; nt < 2; ++nt) {
                    f16x4 bh, bl;   // B-frag: kv[k = quad*4+reg, col = lx]
#pragma unroll
                    for (int reg = 0; reg < 4; ++reg) {
                        float dot = accM[mt][nt][reg]
                                  + accC[mt][nt][reg] * (1.0f / 4096.0f);
                        float e  = fmaf(2.0f * GAMMA, dot,
                                        -GAMMA * (xnr[nt] + sn4[reg]));
                        float kv = __expf(e);
                        _Float16 h = (_Float16)kv;
                        bh[reg] = h;
                        bl[reg] = (_Float16)((kv - (float)h) * 4096.0f);
                    }
                    accO[nt]  = __builtin_amdgcn_mfma_f32_16x16x16f16(
                        afh, bh, accO[nt], 0, 0, 0);
                    accOC[nt] = __builtin_amdgcn_mfma_f32_16x16x16f16(
                        afh, bl, accOC[nt], 0, 0, 0);
                    accOC[nt] = __builtin_amdgcn_mfma_f32_16x16x16f16(
                        afl, bh, accOC[nt], 0, 0, 0);
                    accM[mt][nt] = (f32x4){0.f, 0.f, 0.f, 0.f};
                    accC[mt][nt] = (f32x4){0.f, 0.f, 0.f, 0.f};
                }
            }
        }

        // -- phase bottom: our ds_reads of buf are done (lgkm drained);
        // barrier separates them from next phase's DMA into buf. NO vmcnt.
        asm volatile("s_waitcnt lgkmcnt(0)" ::: "memory");
        __builtin_amdgcn_s_barrier();
        asm volatile("" ::: "memory");
    }

    // cross-wm reduce via 8KB of reused SVs space, then store T (transposed
    // [90][N] layout: 16 lanes -> 64B contiguous, coalesced).
    float* scr = (float*)&SVs[0][0][0];
    if (wm == 0) {
#pragma unroll
        for (int nt = 0; nt < 2; ++nt)
#pragma unroll
            for (int reg = 0; reg < 4; ++reg) {
                int base = ((wn * 2 + nt) * 2) * 256 + (quad * 4 + reg) * 16 + lx;
                scr[base]       = accO[nt][reg];
                scr[base + 256] = accOC[nt][reg];
            }
    }
    __syncthreads();
    if (wm == 1) {
#pragma unroll
        for (int nt = 0; nt < 2; ++nt)
#pragma unroll
            for (int reg = 0; reg < 4; ++reg) {
                int r = quad * 4 + reg;
                if (r < R) {
                    int base = ((wn * 2 + nt) * 2) * 256 + r * 16 + lx;
                    float o  = accO[nt][reg]  + scr[base];
                    float oc = accOC[nt][reg] + scr[base + 256];
                    int n = n0 + wn * 32 + nt * 16 + lx;
                    T[(size_t)(r * 10 + cls) * N + n] = o + oc * (1.0f / 4096.0f);
                }
            }
    }
}

// ---------------- pairwise voting + argmax ----------------------------------
// T is [90][N]: every load below is a coalesced 1KB/wave read.
__global__ __launch_bounds__(256) void vote_kernel(const float* __restrict__ T,
                                                   const float* __restrict__ b,
                                                   int* __restrict__ out) {
    int n = blockIdx.x * blockDim.x + threadIdx.x;
    if (n >= N) return;
    float tv[90];
#pragma unroll
    for (int i = 0; i < 90; ++i) tv[i] = T[(size_t)i * N + n];
    int counts[C];
#pragma unroll
    for (int k = 0; k < C; ++k) counts[k] = 0;
    int p = 0;
#pragma unroll
    for (int i = 0; i < C; ++i) {
#pragma unroll
        for (int j = i + 1; j < C; ++j) {
            float c = tv[i * 10 + j] + tv[(j - 1) * 10 + i] + b[p];
            if (c > 0.f) counts[i]++; else counts[j]++;
            ++p;
        }
    }
    int best = 0;
#pragma unroll
    for (int k = 1; k < C; ++k)
        if (counts[k] > counts[best]) best = k;
    out[n]     = best;
    out[N + n] = best;
}

extern "C" void kernel_launch(void* const* d_in, const int* in_sizes, int n_in,
                              void* d_out, int out_size, void* d_ws, size_t ws_size,
                              hipStream_t stream) {
    const float* x  = (const float*)d_in[0];   // [8192,256]
    const float* sv = (const float*)d_in[1];   // [5000,256]
    const float* a  = (const float*)d_in[2];   // [9,5000]
    const float* b  = (const float*)d_in[3];   // [45]
    int* out = (int*)d_out;

    char* wp = (char*)d_ws;
    _Float16* xh = (_Float16*)wp;  wp += (size_t)N * D * 2;
    _Float16* xl = (_Float16*)wp;  wp += (size_t)N * D * 2;
    _Float16* sh = (_Float16*)wp;  wp += (size_t)S * D * 2;
    _Float16* sl = (_Float16*)wp;  wp += (size_t)S * D * 2;
    float* xnorm  = (float*)wp;    wp += (size_t)N * 4;
    _Float16* ahp = (_Float16*)wp; wp += (size_t)16 * SPAD * 2;
    _Float16* alp = (_Float16*)wp; wp += (size_t)16 * SPAD * 2;
    float* svnp   = (float*)wp;    wp += (size_t)SPAD * 4;
    float* T      = (float*)wp;    // [90][N]

    {   // fused split + norms + a-split + svnp (one launch)
        prep_kernel<<<ROW_BLOCKS + A_BLOCKS, 256, 0, stream>>>(
            x, sv, a, xh, xl, sh, sl, xnorm, ahp, alp, svnp);
    }
    {   // swapped GEMM + PV-MFMA reduce
        dim3 grid(N / 64, C);
        svc_gemm<<<grid, 256, 0, stream>>>(xh, xl, sh, sl, ahp, alp,
                                           xnorm, svnp, T);
    }
    {   // voting
        vote_kernel<<<N / 256, 256, 0, stream>>>(T, b, out);
    }
}